// Round 14
// baseline (110.893 us; speedup 1.0000x reference)
//
#include <hip/hip_runtime.h>
#include <hip/hip_bf16.h>

// ---------------------------------------------------------------------------
// LogicLayer inference (size=1024, prev=1024, batch=16384)
//   out[s,n] = w0[s] + wA[s]*a + wB[s]*b + wAB[s]*a*b,  a = pA@prev, b = pB@prev
// Round 14: geometry change — per-wave 128x128 output (was 128x64).
//   7 schedule variants all pinned at serial-sum(MFMA, LDS-port); the lever
//   left is arithmetic intensity: M*N/(M+N) rises 42.7 -> 64 FLOP/LDS-byte,
//   cutting per-tile LDS reads 192KB -> 128KB. 4 waves (2 panel x 2 col-half),
//   acc[8][8] (256 VGPR) + 4 banks (128 VGPR), launch_bounds(256,1),
//   1 wave/SIMD. Schedule = r12 verbatim (banked quadrants, same stage
//   calendar, one vmcnt(0)+barrier per tile; WAR/RAW audit carries over).
// ---------------------------------------------------------------------------

typedef __attribute__((ext_vector_type(8))) short bf16x8;
typedef __attribute__((ext_vector_type(4))) float f32x4;

__device__ __forceinline__ void gload_lds16(const void* g, void* l) {
    __builtin_amdgcn_global_load_lds(
        (const __attribute__((address_space(1))) void*)g,
        (__attribute__((address_space(3))) void*)l, 16, 0, 0);
}

// ---------------- kernel 1: row softmax of WA/WB -> bf16, + table coefs -----
__global__ __launch_bounds__(256) void softmax_rows_bf16(
    const float* __restrict__ WA, const float* __restrict__ WB,
    __hip_bfloat16* __restrict__ PA, __hip_bfloat16* __restrict__ PB,
    const float* __restrict__ TW, float4* __restrict__ coef,
    int rows, int cols, int size)
{
    const int b = blockIdx.x;
    if (b >= 2 * rows) {
        const int s = (b - 2 * rows) * 256 + threadIdx.x;
        if (s < size) {
            float p[16];
            float mx = -1e30f;
            #pragma unroll
            for (int g = 0; g < 16; ++g) { p[g] = TW[g * size + s]; mx = fmaxf(mx, p[g]); }
            float sum = 0.f;
            #pragma unroll
            for (int g = 0; g < 16; ++g) { p[g] = __expf(p[g] - mx); sum += p[g]; }
            const float inv = 1.0f / sum;
            #pragma unroll
            for (int g = 0; g < 16; ++g) p[g] *= inv;
            float w0  = p[8] + p[9] + p[10] + p[11] + p[12] + p[13] + p[14] + p[15];
            float wA  = p[2] + p[3] + p[6] + p[7] - p[8] - p[9] - p[12] - p[13];
            float wB  = p[4] + p[5] + p[6] + p[7] - p[8] - p[9] - p[10] - p[11];
            float wAB = p[1] - p[2] - p[4] - 2.f * p[6] - p[7]
                      + p[8] + 2.f * p[9] + p[11] + p[13] - p[14];
            coef[s] = make_float4(w0, wA, wB, wAB);
        }
        return;
    }

    const float* W;
    __hip_bfloat16* P;
    if (b < rows) { W = WA + (size_t)b * cols;          P = PA + (size_t)b * cols; }
    else          { W = WB + (size_t)(b - rows) * cols; P = PB + (size_t)(b - rows) * cols; }

    const int t = threadIdx.x;
    const int wave = t >> 6, lane = t & 63;

    float4 v = *(const float4*)&W[t * 4];
    float mx = fmaxf(fmaxf(v.x, v.y), fmaxf(v.z, v.w));
    #pragma unroll
    for (int off = 32; off; off >>= 1) mx = fmaxf(mx, __shfl_xor(mx, off));

    __shared__ float redmax[4];
    __shared__ float redsum[4];
    if (lane == 0) redmax[wave] = mx;
    __syncthreads();
    mx = fmaxf(fmaxf(redmax[0], redmax[1]), fmaxf(redmax[2], redmax[3]));

    float e0 = __expf(v.x - mx), e1 = __expf(v.y - mx);
    float e2 = __expf(v.z - mx), e3 = __expf(v.w - mx);
    float s = e0 + e1 + e2 + e3;
    #pragma unroll
    for (int off = 32; off; off >>= 1) s += __shfl_xor(s, off);
    if (lane == 0) redsum[wave] = s;
    __syncthreads();
    s = redsum[0] + redsum[1] + redsum[2] + redsum[3];

    const float inv = 1.0f / s;
    __align__(8) __hip_bfloat16 o[4];
    o[0] = __float2bfloat16(e0 * inv);
    o[1] = __float2bfloat16(e1 * inv);
    o[2] = __float2bfloat16(e2 * inv);
    o[3] = __float2bfloat16(e3 * inv);
    *(uint2*)&P[t * 4] = *(const uint2*)o;
}

// ---------------- kernel 2: prev (K x N f32) -> prevT (N x K bf16) ----------
__global__ __launch_bounds__(256) void transpose_bf16(
    const float* __restrict__ prev, __hip_bfloat16* __restrict__ prevT,
    int K, int N)
{
    __shared__ float ls[64][65];
    const int k0 = blockIdx.y * 64, n0 = blockIdx.x * 64;
    const int t = threadIdx.x;

    {
        const int kr = t >> 4, nc = (t & 15) * 4;
        #pragma unroll
        for (int i = 0; i < 4; ++i) {
            const int k = i * 16 + kr;
            float4 v = *(const float4*)&prev[(size_t)(k0 + k) * N + n0 + nc];
            ls[k][nc + 0] = v.x; ls[k][nc + 1] = v.y;
            ls[k][nc + 2] = v.z; ls[k][nc + 3] = v.w;
        }
    }
    __syncthreads();
    {
        const int n = t >> 2, kc = (t & 3) * 16;
        __align__(16) __hip_bfloat16 tmp[16];
        #pragma unroll
        for (int j = 0; j < 16; ++j) tmp[j] = __float2bfloat16(ls[kc + j][n]);
        __hip_bfloat16* dst = &prevT[(size_t)(n0 + n) * K + k0 + kc];
        *(uint4*)(dst + 0) = *(const uint4*)&tmp[0];
        *(uint4*)(dst + 8) = *(const uint4*)&tmp[8];
    }
}

// ---------------- kernel 3: 4-wave dual GEMM, per-wave 128x128 --------------
// Block: 256 stacked A-rows (128 pA + 128 pB) x 256 cols, BK=64, 16 K-tiles.
// 4 waves 2(panel wr)x2(col-half wc); per-wave out 128x128 = acc[8][8].
// LDS buffer 64KB: [ApA @0][ApB @16384][B rows0-127 @32768][B rows128-255
// @49152]; 2 buffers @0/65536. Row=128B, chunk-XOR swizzle (as r4..r13).
// Banks: aL(i0-3) aH(i4-7) bL(j0-3) bH(j4-7), read 1 quadrant before use.
constexpr int Kd = 1024;
constexpr int Nd = 16384;

__global__ __launch_bounds__(256, 1) void dual_gemm4(
    const __hip_bfloat16* __restrict__ pA,
    const __hip_bfloat16* __restrict__ pB,
    const __hip_bfloat16* __restrict__ prevT,
    const float4* __restrict__ coef,
    float* __restrict__ out)
{
    __shared__ __align__(16) char smem[131072];

    const int t_ = threadIdx.x;
    const int wave = t_ >> 6, lane = t_ & 63;
    const int wr = wave >> 1, wc = wave & 1;      // wr: 0=pA panel, 1=pB panel
    const int m0 = blockIdx.y * 128;
    const int n0 = blockIdx.x * 256;

    // fragment-read addressing
    const int fr  = lane & 15;
    const int kg  = lane >> 4;
    const int fsw = fr & 7;
    const int c0 = (kg ^ fsw) * 16;               // kstep 0 chunk byte
    const int c1 = ((4 + kg) ^ fsw) * 16;         // kstep 1 chunk byte
    const int aoffs = wr * 16384 + fr * 128;      // + i*2048 (+8192 for i4-7)
    const int boffs = 32768 + (wc * 128 + fr) * 128;  // + j*2048 (+8192 j4-7)

    // staging addressing (pre-swizzled global source); 4 waves cover rows
    // 0-63 with gload pair 1, 64-127 with pair 2 (4 gloads/wave/section)
    const int sr  = lane >> 3;
    const int swz = ((lane & 7) ^ sr) * 8;
    const int r0  = wave * 16 + sr;
    const __hip_bfloat16* gA0 = pA    + (size_t)(m0 + r0) * Kd + swz;
    const __hip_bfloat16* gA1 = pB    + (size_t)(m0 + r0) * Kd + swz;
    const __hip_bfloat16* gB0 = prevT + (size_t)(n0 + r0) * Kd + swz;
    const __hip_bfloat16* gB1 = prevT + (size_t)(n0 + 128 + r0) * Kd + swz;

    f32x4 acc[8][8] = {};
    bf16x8 aL[8], aH[8], bL[8], bH[8];            // disjoint banks, 128 VGPR

#define STG(GP, BB, HOFF, KT) {                                             \
    char* lb = smem + (BB) + (HOFF) + wave * 2048;                          \
    gload_lds16((GP) + (KT), lb);                                           \
    gload_lds16((GP) + (KT) + 8 * Kd, lb + 1024);                           \
    gload_lds16((GP) + (KT) + 64 * Kd, lb + 8192);                          \
    gload_lds16((GP) + (KT) + 72 * Kd, lb + 9216); }

#define RD_AL(BB) _Pragma("unroll") for (int i = 0; i < 4; ++i) {           \
    aL[i*2]   = *(const bf16x8*)(smem + (BB) + aoffs + i * 2048 + c0);      \
    aL[i*2+1] = *(const bf16x8*)(smem + (BB) + aoffs + i * 2048 + c1); }
#define RD_AH(BB) _Pragma("unroll") for (int i = 0; i < 4; ++i) {           \
    aH[i*2]   = *(const bf16x8*)(smem + (BB) + aoffs + 8192 + i * 2048 + c0); \
    aH[i*2+1] = *(const bf16x8*)(smem + (BB) + aoffs + 8192 + i * 2048 + c1); }
#define RD_BL(BB) _Pragma("unroll") for (int j = 0; j < 4; ++j) {           \
    bL[j*2]   = *(const bf16x8*)(smem + (BB) + boffs + j * 2048 + c0);      \
    bL[j*2+1] = *(const bf16x8*)(smem + (BB) + boffs + j * 2048 + c1); }
#define RD_BH(BB) _Pragma("unroll") for (int j = 0; j < 4; ++j) {           \
    bH[j*2]   = *(const bf16x8*)(smem + (BB) + boffs + 8192 + j * 2048 + c0); \
    bH[j*2+1] = *(const bf16x8*)(smem + (BB) + boffs + 8192 + j * 2048 + c1); }

#define VMW(S) asm volatile("s_waitcnt " S ::: "memory")

// 32-MFMA quadrant (4x4 frags x 2 ksteps); register deps only.
#define MMQ(AB, BB, I0, J0)                                                 \
    _Pragma("unroll") for (int i = 0; i < 4; ++i)                           \
    _Pragma("unroll") for (int j = 0; j < 4; ++j)                           \
    _Pragma("unroll") for (int ks = 0; ks < 2; ++ks)                        \
        acc[(I0)+i][(J0)+j] = __builtin_amdgcn_mfma_f32_16x16x32_bf16(      \
            AB[i*2+ks], BB[j*2+ks], acc[(I0)+i][(J0)+j], 0, 0, 0);

// One K-tile = 4 quadrants, r12's calendar. Q1 stage gA(T+1)[8 loads],
// Q2 gB0(T+1)[4], Q3 gB1(T+1)[4]; Q4-top vmcnt(0) drains all (ages 3/2/1
// quadrants). Full drain + barrier => NXT valid for tail reads. WAR: stages
// write NXT whose last reads (tile T-1 pre-barrier) are sealed by T-1's
// barrier; T-1's post-barrier tail reads touch CUR(T), not NXT(T).
#define TILE(T, CURB, NXTB, SG, DOTAIL) {                                   \
    if (SG) { STG(gA0, NXTB, 0, ((T)+1)*64)                                 \
              STG(gA1, NXTB, 16384, ((T)+1)*64) }                           \
    RD_BH(CURB)                                                             \
    MMQ(aL, bL, 0, 0)                                                       \
    if (SG) { STG(gB0, NXTB, 32768, ((T)+1)*64) }                           \
    RD_AH(CURB)                                                             \
    MMQ(aL, bH, 0, 4)                                                       \
    if (SG) { STG(gB1, NXTB, 49152, ((T)+1)*64) }                           \
    MMQ(aH, bH, 4, 4)                                                       \
    VMW("vmcnt(0)");                                                        \
    __builtin_amdgcn_s_barrier();                                           \
    __builtin_amdgcn_sched_barrier(0);                                      \
    if (DOTAIL) { RD_AL(NXTB) }                                             \
    MMQ(aH, bL, 4, 0)                                                       \
    if (DOTAIL) { RD_BL(NXTB) }                                             \
}

    // prologue: stage tile0 -> buf0, drain, preload aL(0)/bL(0)
    STG(gA0, 0, 0,     0)
    STG(gA1, 0, 16384, 0)
    STG(gB0, 0, 32768, 0)
    STG(gB1, 0, 49152, 0)
    VMW("vmcnt(0)");
    __builtin_amdgcn_s_barrier();
    __builtin_amdgcn_sched_barrier(0);
    RD_AL(0) RD_BL(0)

    for (int t = 0; t < 15; ++t) {
        const int cb = (t & 1) << 16;
        TILE(t, cb, cb ^ 65536, 1, 1)
    }
    TILE(15, 65536, 0, 0, 0)

#undef TILE
#undef MMQ
#undef STG
#undef RD_AL
#undef RD_AH
#undef RD_BL
#undef RD_BH
#undef VMW

    // ---- epilogue: exchange b-acc via LDS (128KB), fuse bilinear coefs ----
    __syncthreads();
    if (wr == 1) {
        #pragma unroll
        for (int i = 0; i < 8; ++i) {
            #pragma unroll
            for (int j = 0; j < 8; ++j) {
                const int off = ((((i * 8 + j) * 2 + wc) * 64) + lane) * 16;
                *(f32x4*)(smem + off) = acc[i][j];
            }
        }
    }
    __syncthreads();
    if (wr == 0) {
        const int hi = lane >> 4;
        #pragma unroll
        for (int i = 0; i < 8; ++i) {
            float4 cc[4];
            #pragma unroll
            for (int r = 0; r < 4; ++r) cc[r] = coef[m0 + i * 16 + hi * 4 + r];
            #pragma unroll
            for (int j = 0; j < 8; ++j) {
                const f32x4 bb = *(const f32x4*)(smem + ((((i * 8 + j) * 2 + wc) * 64) + lane) * 16);
                const int n = n0 + wc * 128 + j * 16 + fr;
                #pragma unroll
                for (int r = 0; r < 4; ++r) {
                    const int m = m0 + i * 16 + hi * 4 + r;
                    const float aa = acc[i][j][r];
                    out[(size_t)m * Nd + n] = cc[r].x + cc[r].y * aa + cc[r].z * bb[r]
                                            + cc[r].w * (aa * bb[r]);
                }
            }
        }
    }
}

// ---------------------------------------------------------------------------
extern "C" void kernel_launch(void* const* d_in, const int* in_sizes, int n_in,
                              void* d_out, int out_size, void* d_ws, size_t ws_size,
                              hipStream_t stream)
{
    const float* prev = (const float*)d_in[0];   // (prev_size, batch)
    const float* WA   = (const float*)d_in[1];   // (size, prev_size)
    const float* WB   = (const float*)d_in[2];   // (size, prev_size)
    const float* TW   = (const float*)d_in[3];   // (16, size)
    float* out = (float*)d_out;                  // (size, batch)

    const int size      = in_sizes[3] / 16;          // 1024
    const int prev_size = in_sizes[1] / size;        // 1024
    const int batch     = in_sizes[0] / prev_size;   // 16384

    char* ws = (char*)d_ws;
    __hip_bfloat16* prevT = (__hip_bfloat16*)ws;     // 32MB
    size_t off = (size_t)batch * prev_size * sizeof(__hip_bfloat16);
    __hip_bfloat16* pA = (__hip_bfloat16*)(ws + off);
    off += (size_t)size * prev_size * sizeof(__hip_bfloat16);
    __hip_bfloat16* pB = (__hip_bfloat16*)(ws + off);
    off += (size_t)size * prev_size * sizeof(__hip_bfloat16);
    float4* coef = (float4*)(ws + off);

    const int coef_blocks = (size + 255) / 256;
    softmax_rows_bf16<<<dim3(2 * size + coef_blocks), dim3(256), 0, stream>>>(
        WA, WB, pA, pB, TW, coef, size, prev_size, size);
    transpose_bf16<<<dim3(batch / 64, prev_size / 64), dim3(256), 0, stream>>>(
        prev, prevT, prev_size, batch);
    dual_gemm4<<<dim3(batch / 256, size / 128), dim3(256), 0, stream>>>(
        pA, pB, prevT, coef, out);
}

// Round 15
// 84.527 us; speedup vs baseline: 1.3119x; 1.3119x over previous
//
#include <hip/hip_runtime.h>
#include <hip/hip_bf16.h>

// ---------------------------------------------------------------------------
// LogicLayer inference (size=1024, prev=1024, batch=16384)
//   out[s,n] = w0[s] + wA[s]*a + wB[s]*b + wAB[s]*a*b,  a = pA@prev, b = pB@prev
// Round 15: r12's GEMM (best measured: 65.2us, MfmaUtil 42%, within 8% of
// the structure's serial-sum floor) + ALL prep work merged into ONE kernel:
//   blocks [0,4096): transpose prev f32 -> prevT bf16 (HBM-bound, 96MB)
//   blocks [4096,6144): row softmax of WA/WB -> bf16 (runs concurrently)
//   blocks [6144,6148): table softmax -> bilinear coeffs
// Saves one launch gap and overlaps softmax under the transpose's HBM time.
// r14's 128x128/wave geometry REVERTED (VGPR spill: 256 cap + 91MB scratch).
// ---------------------------------------------------------------------------

typedef __attribute__((ext_vector_type(8))) short bf16x8;
typedef __attribute__((ext_vector_type(4))) float f32x4;

__device__ __forceinline__ void gload_lds16(const void* g, void* l) {
    __builtin_amdgcn_global_load_lds(
        (const __attribute__((address_space(1))) void*)g,
        (__attribute__((address_space(3))) void*)l, 16, 0, 0);
}

// ---------------- kernel 1: fused prep (transpose | softmax | coef) ---------
// Sizes fixed: prev (1024 x 16384) f32; WA/WB (1024 x 1024); TW (16 x 1024).
constexpr int Kp = 1024;     // prev_size
constexpr int Np = 16384;    // batch
constexpr int NTB = (Np / 64) * (Kp / 64);   // 4096 transpose blocks

__global__ __launch_bounds__(256) void prep_fused(
    const float* __restrict__ prev, __hip_bfloat16* __restrict__ prevT,
    const float* __restrict__ WA, const float* __restrict__ WB,
    __hip_bfloat16* __restrict__ PA, __hip_bfloat16* __restrict__ PB,
    const float* __restrict__ TW, float4* __restrict__ coef)
{
    const int bid = blockIdx.x;
    const int t = threadIdx.x;

    if (bid < NTB) {
        // ---- transpose tile: prev (K x N) -> prevT (N x K) bf16 ----
        __shared__ float ls[64][65];
        const int n0 = (bid & 255) * 64;          // N/64 = 256
        const int k0 = (bid >> 8) * 64;
        {
            const int kr = t >> 4, nc = (t & 15) * 4;
            #pragma unroll
            for (int i = 0; i < 4; ++i) {
                const int k = i * 16 + kr;
                float4 v = *(const float4*)&prev[(size_t)(k0 + k) * Np + n0 + nc];
                ls[k][nc + 0] = v.x; ls[k][nc + 1] = v.y;
                ls[k][nc + 2] = v.z; ls[k][nc + 3] = v.w;
            }
        }
        __syncthreads();
        {
            const int n = t >> 2, kc = (t & 3) * 16;
            __align__(16) __hip_bfloat16 tmp[16];
            #pragma unroll
            for (int j = 0; j < 16; ++j) tmp[j] = __float2bfloat16(ls[kc + j][n]);
            __hip_bfloat16* dst = &prevT[(size_t)(n0 + n) * Kp + k0 + kc];
            *(uint4*)(dst + 0) = *(const uint4*)&tmp[0];
            *(uint4*)(dst + 8) = *(const uint4*)&tmp[8];
        }
        return;
    }

    if (bid < NTB + 2048) {
        // ---- row softmax of WA/WB -> bf16 ----
        const int b = bid - NTB;
        const float* W;
        __hip_bfloat16* P;
        if (b < 1024) { W = WA + (size_t)b * Kp;          P = PA + (size_t)b * Kp; }
        else          { W = WB + (size_t)(b - 1024) * Kp; P = PB + (size_t)(b - 1024) * Kp; }

        const int wave = t >> 6, lane = t & 63;
        float4 v = *(const float4*)&W[t * 4];
        float mx = fmaxf(fmaxf(v.x, v.y), fmaxf(v.z, v.w));
        #pragma unroll
        for (int off = 32; off; off >>= 1) mx = fmaxf(mx, __shfl_xor(mx, off));

        __shared__ float redmax[4];
        __shared__ float redsum[4];
        if (lane == 0) redmax[wave] = mx;
        __syncthreads();
        mx = fmaxf(fmaxf(redmax[0], redmax[1]), fmaxf(redmax[2], redmax[3]));

        float e0 = __expf(v.x - mx), e1 = __expf(v.y - mx);
        float e2 = __expf(v.z - mx), e3 = __expf(v.w - mx);
        float s = e0 + e1 + e2 + e3;
        #pragma unroll
        for (int off = 32; off; off >>= 1) s += __shfl_xor(s, off);
        if (lane == 0) redsum[wave] = s;
        __syncthreads();
        s = redsum[0] + redsum[1] + redsum[2] + redsum[3];

        const float inv = 1.0f / s;
        __align__(8) __hip_bfloat16 o[4];
        o[0] = __float2bfloat16(e0 * inv);
        o[1] = __float2bfloat16(e1 * inv);
        o[2] = __float2bfloat16(e2 * inv);
        o[3] = __float2bfloat16(e3 * inv);
        *(uint2*)&P[t * 4] = *(const uint2*)o;
        return;
    }

    // ---- table softmax -> bilinear coeffs ----
    const int s = (bid - NTB - 2048) * 256 + t;
    if (s < 1024) {
        float p[16];
        float mx = -1e30f;
        #pragma unroll
        for (int g = 0; g < 16; ++g) { p[g] = TW[g * 1024 + s]; mx = fmaxf(mx, p[g]); }
        float sum = 0.f;
        #pragma unroll
        for (int g = 0; g < 16; ++g) { p[g] = __expf(p[g] - mx); sum += p[g]; }
        const float inv = 1.0f / sum;
        #pragma unroll
        for (int g = 0; g < 16; ++g) p[g] *= inv;
        float w0  = p[8] + p[9] + p[10] + p[11] + p[12] + p[13] + p[14] + p[15];
        float wA  = p[2] + p[3] + p[6] + p[7] - p[8] - p[9] - p[12] - p[13];
        float wB  = p[4] + p[5] + p[6] + p[7] - p[8] - p[9] - p[10] - p[11];
        float wAB = p[1] - p[2] - p[4] - 2.f * p[6] - p[7]
                  + p[8] + 2.f * p[9] + p[11] + p[13] - p[14];
        coef[s] = make_float4(w0, wA, wB, wAB);
    }
}

// ---------------- kernel 2: banked dual GEMM (r12 verbatim) -----------------
// Block: 256 stacked A-rows (128 pA + 128 pB) x 256 cols, BK=64, 16 K-tiles.
// 8 waves 2(panel)x4(N), per-wave 128x64 out = acc[8][4].
// LDS buffer 64KB: [ApA @0][ApB @16384][B n0-127 @32768][B n128-255 @49152];
// 2 buffers @0/65536. Row=128B, chunk-XOR swizzle.
// Banks: aL(i0-3) aH(i4-7) bL(j0-1) bH(j2-3), read 1 quadrant before use.
constexpr int Kd = 1024;
constexpr int Nd = 16384;

__global__ __launch_bounds__(512, 2) void dual_gemm8(
    const __hip_bfloat16* __restrict__ pA,
    const __hip_bfloat16* __restrict__ pB,
    const __hip_bfloat16* __restrict__ prevT,
    const float4* __restrict__ coef,
    float* __restrict__ out)
{
    __shared__ __align__(16) char smem[131072];

    const int t_ = threadIdx.x;
    const int wave = t_ >> 6, lane = t_ & 63;
    const int wr = wave >> 2, wc = wave & 3;      // wr: 0=pA panel, 1=pB panel
    const int m0 = blockIdx.y * 128;
    const int n0 = blockIdx.x * 256;

    // fragment-read addressing
    const int fr  = lane & 15;
    const int kg  = lane >> 4;
    const int fsw = fr & 7;
    const int c0 = (kg ^ fsw) * 16;               // kstep 0 chunk byte
    const int c1 = ((4 + kg) ^ fsw) * 16;         // kstep 1 chunk byte
    const int aoffs = (wr * 128 + fr) * 128;      // + i*2048 (+8192 for i4-7)
    const int boffs = 32768 + (wc * 64 + fr) * 128;  // + j*2048 (+4096 j2-3)

    // staging addressing (pre-swizzled global source)
    const int sr  = lane >> 3;
    const int swz = ((lane & 7) ^ sr) * 8;
    const int r0  = wave * 16 + sr;
    const __hip_bfloat16* gA0 = pA    + (size_t)(m0 + r0) * Kd + swz;
    const __hip_bfloat16* gA1 = pB    + (size_t)(m0 + r0) * Kd + swz;
    const __hip_bfloat16* gB0 = prevT + (size_t)(n0 + r0) * Kd + swz;
    const __hip_bfloat16* gB1 = prevT + (size_t)(n0 + 128 + r0) * Kd + swz;

    f32x4 acc[8][4] = {};
    bf16x8 aL[8], aH[8], bL[4], bH[4];            // disjoint banks

#define STG(GP, BB, HOFF, KT) {                                             \
    char* lb = smem + (BB) + (HOFF) + wave * 2048;                          \
    gload_lds16((GP) + (KT), lb);                                           \
    gload_lds16((GP) + (KT) + 8 * Kd, lb + 1024); }

#define RD_AL(BB) _Pragma("unroll") for (int i = 0; i < 4; ++i) {           \
    aL[i*2]   = *(const bf16x8*)(smem + (BB) + aoffs + i * 2048 + c0);      \
    aL[i*2+1] = *(const bf16x8*)(smem + (BB) + aoffs + i * 2048 + c1); }
#define RD_AH(BB) _Pragma("unroll") for (int i = 0; i < 4; ++i) {           \
    aH[i*2]   = *(const bf16x8*)(smem + (BB) + aoffs + 8192 + i * 2048 + c0); \
    aH[i*2+1] = *(const bf16x8*)(smem + (BB) + aoffs + 8192 + i * 2048 + c1); }
#define RD_BL(BB) _Pragma("unroll") for (int j = 0; j < 2; ++j) {           \
    bL[j*2]   = *(const bf16x8*)(smem + (BB) + boffs + j * 2048 + c0);      \
    bL[j*2+1] = *(const bf16x8*)(smem + (BB) + boffs + j * 2048 + c1); }
#define RD_BH(BB) _Pragma("unroll") for (int j = 0; j < 2; ++j) {           \
    bH[j*2]   = *(const bf16x8*)(smem + (BB) + boffs + 4096 + j * 2048 + c0); \
    bH[j*2+1] = *(const bf16x8*)(smem + (BB) + boffs + 4096 + j * 2048 + c1); }

#define VMW(S) asm volatile("s_waitcnt " S ::: "memory")

// 16-MFMA quadrant with setprio (r13 A/B showed removing it costs ~4us).
#define MMQ(AB, BB, I0, J0)                                                 \
    __builtin_amdgcn_s_setprio(1);                                          \
    _Pragma("unroll") for (int i = 0; i < 4; ++i)                           \
    _Pragma("unroll") for (int j = 0; j < 2; ++j)                           \
    _Pragma("unroll") for (int ks = 0; ks < 2; ++ks)                        \
        acc[(I0)+i][(J0)+j] = __builtin_amdgcn_mfma_f32_16x16x32_bf16(      \
            AB[i*2+ks], BB[j*2+ks], acc[(I0)+i][(J0)+j], 0, 0, 0);          \
    __builtin_amdgcn_s_setprio(0);

// One K-tile. Stage calendar: Q1 gA(T+1)[4], Q2 gB0(T+1)[2], Q3 gB1(T+1)[2].
// Q4-top vmcnt(0) drains loads aged 3/2/1 quadrants (~1860/1240/620cy);
// ~300cy exposed. Full drain + barrier => NXT valid for tail reads.
#define TILE(T, CURB, NXTB, SG, DOTAIL) {                                   \
    if (SG) { STG(gA0, NXTB, 0, ((T)+1)*64)                                 \
              STG(gA1, NXTB, 16384, ((T)+1)*64) }                           \
    RD_BH(CURB)                                                             \
    MMQ(aL, bL, 0, 0)                                                       \
    if (SG) { STG(gB0, NXTB, 32768, ((T)+1)*64) }                           \
    RD_AH(CURB)                                                             \
    MMQ(aL, bH, 0, 2)                                                       \
    if (SG) { STG(gB1, NXTB, 49152, ((T)+1)*64) }                           \
    MMQ(aH, bH, 4, 2)                                                       \
    VMW("vmcnt(0)");                                                        \
    __builtin_amdgcn_s_barrier();                                           \
    __builtin_amdgcn_sched_barrier(0);                                      \
    if (DOTAIL) { RD_AL(NXTB) }                                             \
    MMQ(aH, bL, 4, 0)                                                       \
    if (DOTAIL) { RD_BL(NXTB) }                                             \
}

    // prologue: stage tile0 -> buf0, drain, preload aL(0)/bL(0)
    STG(gA0, 0, 0,     0)
    STG(gA1, 0, 16384, 0)
    STG(gB0, 0, 32768, 0)
    STG(gB1, 0, 49152, 0)
    VMW("vmcnt(0)");
    __builtin_amdgcn_s_barrier();
    __builtin_amdgcn_sched_barrier(0);
    RD_AL(0) RD_BL(0)

    for (int t = 0; t < 15; ++t) {
        const int cb = (t & 1) << 16;
        TILE(t, cb, cb ^ 65536, 1, 1)
    }
    TILE(15, 65536, 0, 0, 0)

#undef TILE
#undef MMQ
#undef STG
#undef RD_AL
#undef RD_AH
#undef RD_BL
#undef RD_BH
#undef VMW

    // ---- epilogue: exchange b-acc via LDS, fuse bilinear coefficients ----
    __syncthreads();
    if (wr == 1) {
        #pragma unroll
        for (int i = 0; i < 8; ++i) {
            #pragma unroll
            for (int j = 0; j < 4; ++j) {
                const int off = ((((wc * 8 + i) * 4 + j) * 64) + lane) * 16;
                *(f32x4*)(smem + off) = acc[i][j];
            }
        }
    }
    __syncthreads();
    if (wr == 0) {
        const int hi = lane >> 4;
        #pragma unroll
        for (int i = 0; i < 8; ++i) {
            float4 cc[4];
            #pragma unroll
            for (int r = 0; r < 4; ++r) cc[r] = coef[m0 + i * 16 + hi * 4 + r];
            #pragma unroll
            for (int j = 0; j < 4; ++j) {
                const f32x4 bb = *(const f32x4*)(smem + ((((wc * 8 + i) * 4 + j) * 64) + lane) * 16);
                const int n = n0 + wc * 64 + j * 16 + fr;
                #pragma unroll
                for (int r = 0; r < 4; ++r) {
                    const int m = m0 + i * 16 + hi * 4 + r;
                    const float aa = acc[i][j][r];
                    out[(size_t)m * Nd + n] = cc[r].x + cc[r].y * aa + cc[r].z * bb[r]
                                            + cc[r].w * (aa * bb[r]);
                }
            }
        }
    }
}

// ---------------------------------------------------------------------------
extern "C" void kernel_launch(void* const* d_in, const int* in_sizes, int n_in,
                              void* d_out, int out_size, void* d_ws, size_t ws_size,
                              hipStream_t stream)
{
    const float* prev = (const float*)d_in[0];   // (prev_size, batch)
    const float* WA   = (const float*)d_in[1];   // (size, prev_size)
    const float* WB   = (const float*)d_in[2];   // (size, prev_size)
    const float* TW   = (const float*)d_in[3];   // (16, size)
    float* out = (float*)d_out;                  // (size, batch)

    const int size      = in_sizes[3] / 16;          // 1024
    const int prev_size = in_sizes[1] / size;        // 1024
    const int batch     = in_sizes[0] / prev_size;   // 16384

    char* ws = (char*)d_ws;
    __hip_bfloat16* prevT = (__hip_bfloat16*)ws;     // 32MB
    size_t off = (size_t)batch * prev_size * sizeof(__hip_bfloat16);
    __hip_bfloat16* pA = (__hip_bfloat16*)(ws + off);
    off += (size_t)size * prev_size * sizeof(__hip_bfloat16);
    __hip_bfloat16* pB = (__hip_bfloat16*)(ws + off);
    off += (size_t)size * prev_size * sizeof(__hip_bfloat16);
    float4* coef = (float4*)(ws + off);

    const int nprep = (batch / 64) * (prev_size / 64) + 2 * size + (size + 255) / 256;
    prep_fused<<<dim3(nprep), dim3(256), 0, stream>>>(
        prev, prevT, WA, WB, pA, pB, TW, coef);
    dual_gemm8<<<dim3(batch / 256, size / 128), dim3(512), 0, stream>>>(
        pA, pB, prevT, coef, out);
}